// Round 13
// baseline (476.308 us; speedup 1.0000x reference)
//
#include <hip/hip_runtime.h>

typedef __attribute__((ext_vector_type(8))) short short8;
typedef __attribute__((ext_vector_type(4))) float f32x4;

#define N_TOK   16384
#define HDIM    1024
#define OUT_OFF 16777216   // 16384*1024
#define M1ROWS  26216      // 2*(2097+11011)
#define M2ROWS  22022      // 2*11011
#define L2ROW0  4194       // 2*2097

__device__ __forceinline__ unsigned short f2bf(float f) {
  unsigned int u = __float_as_uint(f);
  u += 0x7FFFu + ((u >> 16) & 1u);
  return (unsigned short)(u >> 16);
}

__device__ __forceinline__ void rowmap(int r, int& is_v, int& rank) {
  if (r < 2097)       { is_v = 0; rank = 3276 + r; }
  else if (r < 4194)  { is_v = 1; rank = 1179 + r; }
  else if (r < 15205) { is_v = 0; rank = 1179 + r; }
  else                { is_v = 1; rank = r - 9832; }
}

// ---- stable descending rank ----
__global__ __launch_bounds__(256) void rank_count(const float* __restrict__ imp,
                                                  int* __restrict__ counts) {
  __shared__ float sj[2048];
  const int i = blockIdx.x * 256 + threadIdx.x;
  const int jbase = blockIdx.y * 2048;
  const float vi = imp[i];
  for (int s = threadIdx.x; s < 2048; s += 256) sj[s] = imp[jbase + s];
  __syncthreads();
  int cnt = 0;
  #pragma unroll 8
  for (int s = 0; s < 2048; ++s) {
    float vj = sj[s];
    bool gt = vj > vi;
    bool eq = (vj == vi) && ((jbase + s) < i);
    cnt += (gt || eq) ? 1 : 0;
  }
  atomicAdd(&counts[i], cnt);
}

__global__ __launch_bounds__(256) void scatter_order(const int* __restrict__ counts,
                                                     int* __restrict__ order) {
  int i = blockIdx.x * 256 + threadIdx.x;
  order[counts[i]] = i;
}

// ---- coalesced LDS-tiled weight transpose: dst[N][K] bf16 from src[K][N] f32 ----
// 64x64 tiles; read coalesced over n, write coalesced over k; [64][65] pad.
__global__ __launch_bounds__(256) void wtrans4(
    unsigned short* __restrict__ We0T, const float* __restrict__ We0,
    unsigned short* __restrict__ We1T, const float* __restrict__ We1,
    unsigned short* __restrict__ Wd1T, const float* __restrict__ Wd1,
    unsigned short* __restrict__ Wd0T, const float* __restrict__ Wd0) {
  __shared__ float Tl[64][65];
  int b = blockIdx.x;
  const float* src; unsigned short* dst; int Ks, Ns, Kd, tk, tn;
  if (b < 128)      { src = We0; dst = We0T; Ks = 1024; Ns = 512;  Kd = 1024; tk = b >> 3;          tn = b & 7; }
  else if (b < 256) { src = Wd0; dst = Wd0T; Ks = 512;  Ns = 1024; Kd = 512;  tk = (b - 128) >> 4;  tn = (b - 128) & 15; }
  else if (b < 288) { src = We1; dst = We1T; Ks = 512;  Ns = 204;  Kd = 512;  tk = (b - 256) >> 2;  tn = (b - 256) & 3; }
  else              { src = Wd1; dst = Wd1T; Ks = 204;  Ns = 512;  Kd = 256;  tk = (b - 288) >> 3;  tn = (b - 288) & 7; }
  const int k0 = tk * 64, n0 = tn * 64;
  const int t = threadIdx.x;
  const int cl = t & 63, rw = t >> 6;
  #pragma unroll
  for (int i = 0; i < 16; ++i) {
    int kl = i * 4 + rw;
    int k = k0 + kl, n = n0 + cl;
    Tl[kl][cl] = (k < Ks && n < Ns) ? src[(size_t)k * Ns + n] : 0.f;
  }
  __syncthreads();
  #pragma unroll
  for (int i = 0; i < 16; ++i) {
    int nl = i * 4 + rw;
    dst[(size_t)(n0 + nl) * Kd + (k0 + cl)] = f2bf(Tl[cl][nl]);
  }
}

// ---- gather (level>=1 -> bf16 X) + level-0 copy; 4 rows/block, ILP=4 ----
__global__ __launch_bounds__(256) void gathercopy(
    unsigned short* __restrict__ X,
    const float* __restrict__ keys, const float* __restrict__ values,
    const int* __restrict__ order, float* __restrict__ out) {
  int b = blockIdx.x;
  int lane = threadIdx.x & 63;
  if (b < 6554) {                   // gather: 26216 = 6554*4 exact
    int r = b * 4 + (threadIdx.x >> 6);
    int is_v, rank; rowmap(r, is_v, rank);
    int token = order[rank];
    const float* src = (is_v ? values : keys) + (size_t)token * HDIM + lane * 16;
    float4 f0 = *reinterpret_cast<const float4*>(src);
    float4 f1 = *reinterpret_cast<const float4*>(src + 4);
    float4 f2 = *reinterpret_cast<const float4*>(src + 8);
    float4 f3 = *reinterpret_cast<const float4*>(src + 12);
    unsigned short* dst = X + (size_t)r * HDIM + lane * 16;
    ushort4 h;
    h.x = f2bf(f0.x); h.y = f2bf(f0.y); h.z = f2bf(f0.z); h.w = f2bf(f0.w);
    *reinterpret_cast<ushort4*>(dst) = h;
    h.x = f2bf(f1.x); h.y = f2bf(f1.y); h.z = f2bf(f1.z); h.w = f2bf(f1.w);
    *reinterpret_cast<ushort4*>(dst + 4) = h;
    h.x = f2bf(f2.x); h.y = f2bf(f2.y); h.z = f2bf(f2.z); h.w = f2bf(f2.w);
    *reinterpret_cast<ushort4*>(dst + 8) = h;
    h.x = f2bf(f3.x); h.y = f2bf(f3.y); h.z = f2bf(f3.z); h.w = f2bf(f3.w);
    *reinterpret_cast<ushort4*>(dst + 12) = h;
  } else {                          // level-0 copy: 6552 = 1638*4
    int idx = (b - 6554) * 4 + (threadIdx.x >> 6);
    int is_v = idx & 1, rank = idx >> 1;
    int token = order[rank];
    const float* src = (is_v ? values : keys) + (size_t)token * HDIM + lane * 16;
    float* dst = out + (is_v ? OUT_OFF : 0) + (size_t)token * HDIM + lane * 16;
    float4 f0 = *reinterpret_cast<const float4*>(src);
    float4 f1 = *reinterpret_cast<const float4*>(src + 4);
    float4 f2 = *reinterpret_cast<const float4*>(src + 8);
    float4 f3 = *reinterpret_cast<const float4*>(src + 12);
    *reinterpret_cast<float4*>(dst)      = f0;
    *reinterpret_cast<float4*>(dst + 4)  = f1;
    *reinterpret_cast<float4*>(dst + 8)  = f2;
    *reinterpret_cast<float4*>(dst + 12) = f3;
  }
}

#define GLDS16(g, l) __builtin_amdgcn_global_load_lds( \
    (const __attribute__((address_space(1))) void*)(g), \
    (__attribute__((address_space(3))) void*)(l), 16, 0, 0)

// ---- tiled bf16 GEMM: 128x128, 4 waves, BK=32, 2-slot ring (32 KB ->
// 5 blocks/CU). Per iter: {counted vmcnt(4) -> barrier -> 8 ds_read_b128 ->
// lgkmcnt(0) -> barrier (slot retired block-wide) -> refill slot with t+2 ->
// 16 MFMA}. Never drain vmcnt to 0 mid-loop. R4-proven XOR swizzle.
// XCD-bijective block swizzle. MODE 0: bf16 store. MODE 1: LDS-staged
// f32x4 scatter (Cl[64][128] = exactly the 32 KB) via rowmap/order.
template<int MODE, int K>
__global__ __launch_bounds__(256, 5) void g128(
    const unsigned short* __restrict__ A, int M,
    const unsigned short* __restrict__ Bt, int N,
    const float* __restrict__ bias, int Nbias,
    unsigned short* __restrict__ Cbf, int ldc,
    float* __restrict__ outf, const int* __restrict__ order,
    int NP, int NC) {
  constexpr int NH = K / 32;
  __shared__ __align__(16) unsigned short S[2][8192];  // slot: A[128][32] | B[128][32]

  const int bid = blockIdx.x;
  const int r8 = bid & 7, rest = bid >> 3;
  const int c8 = rest % NC, q8 = rest / NC;
  const int p8 = q8 * 8 + r8;
  if (p8 >= NP) return;
  const int row0 = p8 * 128, col0 = c8 * 128;

  const int tid = threadIdx.x;
  const int wave = tid >> 6, lane = tid & 63;
  const int wm = wave >> 1, wn = wave & 1;
  const int fr = lane & 15, lch = lane >> 4;

  const int lrow = lane >> 2;
  const int sswz = (((lane & 3) ^ ((lane >> 3) & 3)) << 3);
  const unsigned short* gp[4];
  int ldso[4];
  #pragma unroll
  for (int j = 0; j < 4; ++j) {
    const int g = wave * 4 + j;
    const bool isA = g < 8;
    int rr = isA ? (row0 + g * 16 + lrow) : (col0 + (g - 8) * 16 + lrow);
    const int lim = isA ? M : N;
    if (rr >= lim) rr = 0;
    gp[j] = (isA ? A : Bt) + (size_t)rr * K + sswz;
    ldso[j] = g * 512;
  }

  const int qoff = ((lch ^ ((fr >> 1) & 3)) << 3);
  const int abase = (wm * 64 + fr) * 32 + qoff;
  const int bbase = 4096 + (wn * 64 + fr) * 32 + qoff;

  f32x4 acc[4][4] = {};

  // prologue: tiles 0,1 -> slots 0,1 (8 outstanding/wave)
  #pragma unroll
  for (int j = 0; j < 4; ++j) GLDS16(gp[j], S[0] + ldso[j]);
  #pragma unroll
  for (int j = 0; j < 4; ++j) GLDS16(gp[j] + 32, S[1] + ldso[j]);

  #pragma unroll 1
  for (int t = 0; t < NH; ++t) {
    const int s = t & 1;
    if (t + 1 < NH) asm volatile("s_waitcnt vmcnt(4)" ::: "memory");  // tile t landed
    else            asm volatile("s_waitcnt vmcnt(0)" ::: "memory");
    __builtin_amdgcn_s_barrier();
    __builtin_amdgcn_sched_barrier(0);
    const unsigned short* sl = S[s];
    short8 a[4], b[4];
    #pragma unroll
    for (int m = 0; m < 4; ++m)
      a[m] = *reinterpret_cast<const short8*>(sl + abase + m * 512);
    #pragma unroll
    for (int n = 0; n < 4; ++n)
      b[n] = *reinterpret_cast<const short8*>(sl + bbase + n * 512);
    asm volatile("s_waitcnt lgkmcnt(0)" ::: "memory");   // my reads in regs
    __builtin_amdgcn_sched_barrier(0);
    __builtin_amdgcn_s_barrier();                        // slot s retired block-wide
    if (t + 2 < NH) {                                    // refill slot s with t+2
      const int kc = (t + 2) * 32;
      #pragma unroll
      for (int j = 0; j < 4; ++j) GLDS16(gp[j] + kc, S[s] + ldso[j]);
    }
    __builtin_amdgcn_s_setprio(1);
    #pragma unroll
    for (int m = 0; m < 4; ++m)
      #pragma unroll
      for (int n = 0; n < 4; ++n)
        acc[m][n] = __builtin_amdgcn_mfma_f32_16x16x32_bf16(a[m], b[n], acc[m][n], 0, 0, 0);
    __builtin_amdgcn_s_setprio(0);
  }

  const int orow = lch * 4;
  if (MODE == 0) {
    #pragma unroll
    for (int m = 0; m < 4; ++m)
      #pragma unroll
      for (int n = 0; n < 4; ++n)
        #pragma unroll
        for (int j = 0; j < 4; ++j) {
          int r = row0 + wm * 64 + m * 16 + orow + j;
          int c = col0 + wn * 64 + n * 16 + fr;
          if (r < M && c < N) {
            float v = acc[m][n][j] + (c < Nbias ? bias[c] : 0.f);
            Cbf[(size_t)r * ldc + c] = f2bf(fmaxf(v, 0.f));
          }
        }
  } else {
    // LDS-staged scatter: 2 bands of 64 rows; Cl[64][128] f32 = 32 KB exact.
    float* Cl = (float*)S;
    #pragma unroll 1
    for (int p = 0; p < 2; ++p) {
      __builtin_amdgcn_s_barrier();      // band buffer free
      if (wm == p) {                     // waves 2p, 2p+1 own this band
        #pragma unroll
        for (int m = 0; m < 4; ++m)
          #pragma unroll
          for (int n = 0; n < 4; ++n)
            #pragma unroll
            for (int j = 0; j < 4; ++j) {
              int rr = m * 16 + orow + j;          // 0..63
              int cc = wn * 64 + n * 16 + fr;      // 0..127
              float v = acc[m][n][j] + bias[col0 + cc];
              Cl[rr * 128 + cc] = fmaxf(v, 0.f);
            }
      }
      __builtin_amdgcn_s_barrier();      // band staged
      #pragma unroll
      for (int u = 0; u < 8; ++u) {
        int unit = tid + u * 256;        // 64 rows x 32 chunks
        int rr = unit >> 5, ch = unit & 31;
        int r = row0 + p * 64 + rr;
        if (r < M) {
          int iv, rk; rowmap(r, iv, rk);
          int token = order[rk];
          f32x4 v = *reinterpret_cast<const f32x4*>(Cl + rr * 128 + ch * 4);
          *reinterpret_cast<f32x4*>(outf + (size_t)(iv ? OUT_OFF : 0) +
                                    (size_t)token * HDIM + col0 + ch * 4) = v;
        }
      }
    }
  }
}

static inline int swzg(int NP, int NC) { return 8 * NC * ((NP + 7) / 8); }

extern "C" void kernel_launch(void* const* d_in, const int* in_sizes, int n_in,
                              void* d_out, int out_size, void* d_ws, size_t ws_size,
                              hipStream_t stream) {
  const float* keys   = (const float*)d_in[0];
  const float* values = (const float*)d_in[1];
  const float* imp    = (const float*)d_in[2];
  const float* We0    = (const float*)d_in[3];
  const float* be0    = (const float*)d_in[4];
  const float* We1    = (const float*)d_in[5];
  const float* be1    = (const float*)d_in[6];
  const float* Wd0    = (const float*)d_in[7];
  const float* bd0    = (const float*)d_in[8];
  const float* Wd1    = (const float*)d_in[9];
  const float* bd1    = (const float*)d_in[10];

  char* ws = (char*)d_ws;
  int* counts           = (int*)(ws);                       // 64 KB
  int* order            = (int*)(ws + 65536);               // 64 KB
  unsigned short* We0T  = (unsigned short*)(ws + 131072);   // [512][1024]
  unsigned short* We1T  = (unsigned short*)(ws + 1179648);  // [256][512], rows 204+ zero
  unsigned short* Wd1T  = (unsigned short*)(ws + 1441792);  // [512][256], cols 204+ zero
  unsigned short* Wd0T  = (unsigned short*)(ws + 1703936);  // [1024][512]
  unsigned short* Y     = (unsigned short*)(ws + 2752512);  // [26216][512]
  unsigned short* Z     = (unsigned short*)(ws + 29597696); // [22022][256]
  unsigned short* X     = (unsigned short*)(ws + 40872960); // [26216][1024]
  float* outf = (float*)d_out;

  hipMemsetAsync(counts, 0, 65536, stream);
  rank_count<<<dim3(64, 8), 256, 0, stream>>>(imp, counts);
  scatter_order<<<64, 256, 0, stream>>>(counts, order);

  wtrans4<<<320, 256, 0, stream>>>(We0T, We0, We1T, We1, Wd1T, Wd1, Wd0T, Wd0);
  gathercopy<<<6554 + 1638, 256, 0, stream>>>(X, keys, values, order, outf);

  // GEMM1: Y = relu(X @ We0 + be0)   [26216 x 1024] x [1024 x 512]
  g128<0, 1024><<<swzg(205, 4), 256, 0, stream>>>(
      X, M1ROWS, We0T, 512, be0, 512, Y, 512, nullptr, nullptr, 205, 4);

  // GEMM2a: Z = relu(Y_l2 @ We1 + be1)  [22022 x 512] x [512 x 256pad]
  g128<0, 512><<<swzg(173, 2), 256, 0, stream>>>(
      Y + (size_t)L2ROW0 * 512, M2ROWS, We1T, 256, be1, 204, Z, 256,
      nullptr, nullptr, 173, 2);

  // GEMM2b: Y_l2 = relu(Z @ Wd1 + bd1)  [22022 x 256] x [256 x 512]
  g128<0, 256><<<swzg(173, 4), 256, 0, stream>>>(
      Z, M2ROWS, Wd1T, 512, bd1, 512, Y + (size_t)L2ROW0 * 512, 512,
      nullptr, nullptr, 173, 4);

  // GEMM3: out = relu(Y @ Wd0 + bd0), LDS-staged f32x4 scatter
  g128<1, 512><<<swzg(205, 8), 256, 0, stream>>>(
      Y, M1ROWS, Wd0T, 1024, bd0, 1024, nullptr, 0, outf, order, 205, 8);
}

// Round 14
// 271.241 us; speedup vs baseline: 1.7560x; 1.7560x over previous
//
#include <hip/hip_runtime.h>

typedef __attribute__((ext_vector_type(8))) short short8;
typedef __attribute__((ext_vector_type(4))) float f32x4;

#define N_TOK   16384
#define HDIM    1024
#define OUT_OFF 16777216   // 16384*1024
#define M1ROWS  26216      // 2*(2097+11011)
#define M2ROWS  22022      // 2*11011
#define L2ROW0  4194       // 2*2097

__device__ __forceinline__ unsigned short f2bf(float f) {
  unsigned int u = __float_as_uint(f);
  u += 0x7FFFu + ((u >> 16) & 1u);
  return (unsigned short)(u >> 16);
}

__device__ __forceinline__ void rowmap(int r, int& is_v, int& rank) {
  if (r < 2097)       { is_v = 0; rank = 3276 + r; }
  else if (r < 4194)  { is_v = 1; rank = 1179 + r; }
  else if (r < 15205) { is_v = 0; rank = 1179 + r; }
  else                { is_v = 1; rank = r - 9832; }
}

// ---- stable descending rank ----
__global__ __launch_bounds__(256) void rank_count(const float* __restrict__ imp,
                                                  int* __restrict__ counts) {
  __shared__ float sj[2048];
  const int i = blockIdx.x * 256 + threadIdx.x;
  const int jbase = blockIdx.y * 2048;
  const float vi = imp[i];
  for (int s = threadIdx.x; s < 2048; s += 256) sj[s] = imp[jbase + s];
  __syncthreads();
  int cnt = 0;
  #pragma unroll 8
  for (int s = 0; s < 2048; ++s) {
    float vj = sj[s];
    bool gt = vj > vi;
    bool eq = (vj == vi) && ((jbase + s) < i);
    cnt += (gt || eq) ? 1 : 0;
  }
  atomicAdd(&counts[i], cnt);
}

__global__ __launch_bounds__(256) void scatter_order(const int* __restrict__ counts,
                                                     int* __restrict__ order) {
  int i = blockIdx.x * 256 + threadIdx.x;
  order[counts[i]] = i;
}

// ---- merged prep: coalesced LDS-tiled weight transpose + gather + level-0 copy ----
// blocks [0,320): 64x64-tile transpose (read coalesced over n, write over k)
// blocks [320, 320+6554): gather level>=1 rows -> bf16 X; 4 rows/blk, ILP=4
// blocks [320+6554, +1638): level-0 f32 passthrough, 4 rows/blk, ILP=4
__global__ __launch_bounds__(256) void prep2(
    unsigned short* __restrict__ We0T, const float* __restrict__ We0,
    unsigned short* __restrict__ We1T, const float* __restrict__ We1,
    unsigned short* __restrict__ Wd1T, const float* __restrict__ Wd1,
    unsigned short* __restrict__ Wd0T, const float* __restrict__ Wd0,
    unsigned short* __restrict__ X,
    const float* __restrict__ keys, const float* __restrict__ values,
    const int* __restrict__ order, float* __restrict__ out) {
  int b = blockIdx.x;
  if (b < 320) {
    __shared__ float Tl[64][65];
    const float* src; unsigned short* dst; int Ks, Ns, Kd, tk, tn;
    if (b < 128)      { src = We0; dst = We0T; Ks = 1024; Ns = 512;  Kd = 1024; tk = b >> 3;         tn = b & 7; }
    else if (b < 256) { src = Wd0; dst = Wd0T; Ks = 512;  Ns = 1024; Kd = 512;  tk = (b - 128) >> 4; tn = (b - 128) & 15; }
    else if (b < 288) { src = We1; dst = We1T; Ks = 512;  Ns = 204;  Kd = 512;  tk = (b - 256) >> 2; tn = (b - 256) & 3; }
    else              { src = Wd1; dst = Wd1T; Ks = 204;  Ns = 512;  Kd = 256;  tk = (b - 288) >> 3; tn = (b - 288) & 7; }
    const int k0 = tk * 64, n0 = tn * 64;
    const int t = threadIdx.x;
    const int cl = t & 63, rw = t >> 6;
    #pragma unroll
    for (int i = 0; i < 16; ++i) {
      int kl = i * 4 + rw;
      int k = k0 + kl, n = n0 + cl;
      Tl[kl][cl] = (k < Ks && n < Ns) ? src[(size_t)k * Ns + n] : 0.f;
    }
    __syncthreads();
    #pragma unroll
    for (int i = 0; i < 16; ++i) {
      int nl = i * 4 + rw;
      dst[(size_t)(n0 + nl) * Kd + (k0 + cl)] = f2bf(Tl[cl][nl]);
    }
  } else if (b < 320 + 6554) {      // gather: 26216 = 6554*4 exact
    int r = (b - 320) * 4 + (threadIdx.x >> 6);
    int lane = threadIdx.x & 63;
    int is_v, rank; rowmap(r, is_v, rank);
    int token = order[rank];
    const float* src = (is_v ? values : keys) + (size_t)token * HDIM + lane * 16;
    float4 f0 = *reinterpret_cast<const float4*>(src);
    float4 f1 = *reinterpret_cast<const float4*>(src + 4);
    float4 f2 = *reinterpret_cast<const float4*>(src + 8);
    float4 f3 = *reinterpret_cast<const float4*>(src + 12);
    unsigned short* dst = X + (size_t)r * HDIM + lane * 16;
    ushort4 h;
    h.x = f2bf(f0.x); h.y = f2bf(f0.y); h.z = f2bf(f0.z); h.w = f2bf(f0.w);
    *reinterpret_cast<ushort4*>(dst) = h;
    h.x = f2bf(f1.x); h.y = f2bf(f1.y); h.z = f2bf(f1.z); h.w = f2bf(f1.w);
    *reinterpret_cast<ushort4*>(dst + 4) = h;
    h.x = f2bf(f2.x); h.y = f2bf(f2.y); h.z = f2bf(f2.z); h.w = f2bf(f2.w);
    *reinterpret_cast<ushort4*>(dst + 8) = h;
    h.x = f2bf(f3.x); h.y = f2bf(f3.y); h.z = f2bf(f3.z); h.w = f2bf(f3.w);
    *reinterpret_cast<ushort4*>(dst + 12) = h;
  } else {                          // level-0 copy: 6552 = 1638*4
    int idx = (b - (320 + 6554)) * 4 + (threadIdx.x >> 6);
    int lane = threadIdx.x & 63;
    int is_v = idx & 1, rank = idx >> 1;
    int token = order[rank];
    const float* src = (is_v ? values : keys) + (size_t)token * HDIM + lane * 16;
    float* dst = out + (is_v ? OUT_OFF : 0) + (size_t)token * HDIM + lane * 16;
    float4 f0 = *reinterpret_cast<const float4*>(src);
    float4 f1 = *reinterpret_cast<const float4*>(src + 4);
    float4 f2 = *reinterpret_cast<const float4*>(src + 8);
    float4 f3 = *reinterpret_cast<const float4*>(src + 12);
    *reinterpret_cast<float4*>(dst)      = f0;
    *reinterpret_cast<float4*>(dst + 4)  = f1;
    *reinterpret_cast<float4*>(dst + 8)  = f2;
    *reinterpret_cast<float4*>(dst + 12) = f3;
  }
}

#define GLDS16(g, l) __builtin_amdgcn_global_load_lds( \
    (const __attribute__((address_space(1))) void*)(g), \
    (__attribute__((address_space(3))) void*)(l), 16, 0, 0)

// ---- tiled bf16 GEMM (R11 core, byte-identical): 128x128, 4 waves, BK=32,
// 3-slot LDS ring (48 KB, 3 blocks/CU). Per iter ONE barrier: {counted
// vmcnt(4) -> barrier -> 8 ds_read_b128 -> refill freed slot (t+2) ->
// 16 MFMA (compiler lgkm waits)}. Never drain vmcnt to 0 mid-loop.
// R4-proven XOR swizzle (0 conflicts). XCD-bijective block swizzle.
// MODE 0: bf16 store. MODE 1: LDS-staged f32x4 scatter, padded Cl[64][132].
template<int MODE, int K>
__global__ __launch_bounds__(256, 4) void g128(
    const unsigned short* __restrict__ A, int M,
    const unsigned short* __restrict__ Bt, int N,
    const float* __restrict__ bias, int Nbias,
    unsigned short* __restrict__ Cbf, int ldc,
    float* __restrict__ outf, const int* __restrict__ order,
    int NP, int NC) {
  constexpr int NH = K / 32;
  __shared__ __align__(16) unsigned short S[3][8192];  // slot: A[128][32] | B[128][32]

  const int bid = blockIdx.x;
  const int r8 = bid & 7, rest = bid >> 3;
  const int c8 = rest % NC, q8 = rest / NC;
  const int p8 = q8 * 8 + r8;
  if (p8 >= NP) return;
  const int row0 = p8 * 128, col0 = c8 * 128;

  const int tid = threadIdx.x;
  const int wave = tid >> 6, lane = tid & 63;
  const int wm = wave >> 1, wn = wave & 1;
  const int fr = lane & 15, lch = lane >> 4;

  const int lrow = lane >> 2;
  const int sswz = (((lane & 3) ^ ((lane >> 3) & 3)) << 3);
  const unsigned short* gp[4];
  int ldso[4];
  #pragma unroll
  for (int j = 0; j < 4; ++j) {
    const int g = wave * 4 + j;
    const bool isA = g < 8;
    int rr = isA ? (row0 + g * 16 + lrow) : (col0 + (g - 8) * 16 + lrow);
    const int lim = isA ? M : N;
    if (rr >= lim) rr = 0;
    gp[j] = (isA ? A : Bt) + (size_t)rr * K + sswz;
    ldso[j] = g * 512;
  }

  const int qoff = ((lch ^ ((fr >> 1) & 3)) << 3);
  const int abase = (wm * 64 + fr) * 32 + qoff;
  const int bbase = 4096 + (wn * 64 + fr) * 32 + qoff;

  f32x4 acc[4][4] = {};

  #pragma unroll
  for (int j = 0; j < 4; ++j) GLDS16(gp[j], S[0] + ldso[j]);
  #pragma unroll
  for (int j = 0; j < 4; ++j) GLDS16(gp[j] + 32, S[1] + ldso[j]);

  int cur = 0;
  #pragma unroll 1
  for (int t = 0; t < NH; ++t) {
    if (t + 1 < NH) asm volatile("s_waitcnt vmcnt(4)" ::: "memory");
    else            asm volatile("s_waitcnt vmcnt(0)" ::: "memory");
    __builtin_amdgcn_s_barrier();
    __builtin_amdgcn_sched_barrier(0);
    const unsigned short* sl = S[cur];
    short8 a[4], b[4];
    #pragma unroll
    for (int m = 0; m < 4; ++m)
      a[m] = *reinterpret_cast<const short8*>(sl + abase + m * 512);
    #pragma unroll
    for (int n = 0; n < 4; ++n)
      b[n] = *reinterpret_cast<const short8*>(sl + bbase + n * 512);
    if (t + 2 < NH) {
      const int kc = (t + 2) * 32;
      int nb = cur + 2; if (nb >= 3) nb -= 3;
      #pragma unroll
      for (int j = 0; j < 4; ++j) GLDS16(gp[j] + kc, S[nb] + ldso[j]);
    }
    #pragma unroll
    for (int m = 0; m < 4; ++m)
      #pragma unroll
      for (int n = 0; n < 4; ++n)
        acc[m][n] = __builtin_amdgcn_mfma_f32_16x16x32_bf16(a[m], b[n], acc[m][n], 0, 0, 0);
    cur = (cur == 2) ? 0 : cur + 1;
  }

  const int orow = lch * 4;
  if (MODE == 0) {
    #pragma unroll
    for (int m = 0; m < 4; ++m)
      #pragma unroll
      for (int n = 0; n < 4; ++n)
        #pragma unroll
        for (int j = 0; j < 4; ++j) {
          int r = row0 + wm * 64 + m * 16 + orow + j;
          int c = col0 + wn * 64 + n * 16 + fr;
          if (r < M && c < N) {
            float v = acc[m][n][j] + (c < Nbias ? bias[c] : 0.f);
            Cbf[(size_t)r * ldc + c] = f2bf(fmaxf(v, 0.f));
          }
        }
  } else {
    float* Cl = (float*)S;               // [64][132] f32 = 33.8 KB (padded)
    #pragma unroll 1
    for (int p = 0; p < 2; ++p) {
      __builtin_amdgcn_s_barrier();
      if (wm == p) {
        #pragma unroll
        for (int m = 0; m < 4; ++m)
          #pragma unroll
          for (int n = 0; n < 4; ++n)
            #pragma unroll
            for (int j = 0; j < 4; ++j) {
              int rr = m * 16 + orow + j;
              int cc = wn * 64 + n * 16 + fr;
              float v = acc[m][n][j] + bias[col0 + cc];
              Cl[rr * 132 + cc] = fmaxf(v, 0.f);
            }
      }
      __builtin_amdgcn_s_barrier();
      #pragma unroll
      for (int u = 0; u < 8; ++u) {
        int unit = tid + u * 256;
        int rr = unit >> 5, ch = unit & 31;
        int r = row0 + p * 64 + rr;
        if (r < M) {
          int iv, rk; rowmap(r, iv, rk);
          int token = order[rk];
          f32x4 v = *reinterpret_cast<const f32x4*>(Cl + rr * 132 + ch * 4);
          *reinterpret_cast<f32x4*>(outf + (size_t)(iv ? OUT_OFF : 0) +
                                    (size_t)token * HDIM + col0 + ch * 4) = v;
        }
      }
    }
  }
}

static inline int swzg(int NP, int NC) { return 8 * NC * ((NP + 7) / 8); }

extern "C" void kernel_launch(void* const* d_in, const int* in_sizes, int n_in,
                              void* d_out, int out_size, void* d_ws, size_t ws_size,
                              hipStream_t stream) {
  const float* keys   = (const float*)d_in[0];
  const float* values = (const float*)d_in[1];
  const float* imp    = (const float*)d_in[2];
  const float* We0    = (const float*)d_in[3];
  const float* be0    = (const float*)d_in[4];
  const float* We1    = (const float*)d_in[5];
  const float* be1    = (const float*)d_in[6];
  const float* Wd0    = (const float*)d_in[7];
  const float* bd0    = (const float*)d_in[8];
  const float* Wd1    = (const float*)d_in[9];
  const float* bd1    = (const float*)d_in[10];

  char* ws = (char*)d_ws;
  int* counts           = (int*)(ws);                       // 64 KB
  int* order            = (int*)(ws + 65536);               // 64 KB
  unsigned short* We0T  = (unsigned short*)(ws + 131072);   // [512][1024]
  unsigned short* We1T  = (unsigned short*)(ws + 1179648);  // [256][512], rows 204+ zero
  unsigned short* Wd1T  = (unsigned short*)(ws + 1441792);  // [512][256], cols 204+ zero
  unsigned short* Wd0T  = (unsigned short*)(ws + 1703936);  // [1024][512]
  unsigned short* Y     = (unsigned short*)(ws + 2752512);  // [26216][512]
  unsigned short* Z     = (unsigned short*)(ws + 29597696); // [22022][256]
  unsigned short* X     = (unsigned short*)(ws + 40872960); // [26216][1024]
  float* outf = (float*)d_out;

  hipMemsetAsync(counts, 0, 65536, stream);
  rank_count<<<dim3(64, 8), 256, 0, stream>>>(imp, counts);
  scatter_order<<<64, 256, 0, stream>>>(counts, order);

  // merged prep: coalesced weight transpose + gather (ILP=4) + level-0 copy
  prep2<<<320 + 6554 + 1638, 256, 0, stream>>>(
      We0T, We0, We1T, We1, Wd1T, Wd1, Wd0T, Wd0, X, keys, values, order, outf);

  // GEMM1: Y = relu(X @ We0 + be0)   [26216 x 1024] x [1024 x 512]
  g128<0, 1024><<<swzg(205, 4), 256, 0, stream>>>(
      X, M1ROWS, We0T, 512, be0, 512, Y, 512, nullptr, nullptr, 205, 4);

  // GEMM2a: Z = relu(Y_l2 @ We1 + be1)  [22022 x 512] x [512 x 256pad]
  g128<0, 512><<<swzg(173, 2), 256, 0, stream>>>(
      Y + (size_t)L2ROW0 * 512, M2ROWS, We1T, 256, be1, 204, Z, 256,
      nullptr, nullptr, 173, 2);

  // GEMM2b: Y_l2 = relu(Z @ Wd1 + bd1)  [22022 x 256] x [256 x 512]
  g128<0, 256><<<swzg(173, 4), 256, 0, stream>>>(
      Z, M2ROWS, Wd1T, 512, bd1, 512, Y + (size_t)L2ROW0 * 512, 512,
      nullptr, nullptr, 173, 4);

  // GEMM3: out = relu(Y @ Wd0 + bd0), LDS-staged f32x4 scatter
  g128<1, 512><<<swzg(205, 8), 256, 0, stream>>>(
      Y, M1ROWS, Wd0T, 1024, bd0, 1024, nullptr, 0, outf, order, 205, 8);
}